// Round 1
// baseline (104.773 us; speedup 1.0000x reference)
//
#include <hip/hip_runtime.h>

// Block Hadamard transform, block=128, x:(4,4096,4096) fp32, y = (x blocked) @ H
// H = Sylvester Hadamard / sqrt(128)  ==> natural-order FWHT * (1/sqrt(128)).
//
// Each lane loads one float4 (elements 4l..4l+3 of a 128-block); a 32-lane
// half-wave holds one full block. Butterfly stages:
//   h=1,2   : in-register within the float4
//   h=4..64 : __shfl_xor with mask h/4 = 1,2,4,8,16 (stays within 32-lane half)

__global__ __launch_bounds__(256) void BlockHadamardTransform_88957362634992_kernel(
    const float4* __restrict__ x, float4* __restrict__ y, int n4) {
    const float scale = 0.08838834764831845f;  // 1/sqrt(128)
    const int lane = threadIdx.x & 63;
    const int stride = gridDim.x * blockDim.x;
    for (int g = blockIdx.x * blockDim.x + threadIdx.x; g < n4; g += stride) {
        float4 v = x[g];
        // stage h=1: pairs (4l,4l+1),(4l+2,4l+3)
        float a0 = v.x + v.y;
        float a1 = v.x - v.y;
        float a2 = v.z + v.w;
        float a3 = v.z - v.w;
        // stage h=2: pairs (4l,4l+2),(4l+1,4l+3)
        float b0 = a0 + a2;
        float b1 = a1 + a3;
        float b2 = a0 - a2;
        float b3 = a1 - a3;
        // stages h=4,8,16,32,64 -> xor lane mask m = h/4
        #pragma unroll
        for (int m = 1; m <= 16; m <<= 1) {
            float p0 = __shfl_xor(b0, m);
            float p1 = __shfl_xor(b1, m);
            float p2 = __shfl_xor(b2, m);
            float p3 = __shfl_xor(b3, m);
            const bool up = (lane & m) != 0;
            b0 = up ? (p0 - b0) : (b0 + p0);
            b1 = up ? (p1 - b1) : (b1 + p1);
            b2 = up ? (p2 - b2) : (b2 + p2);
            b3 = up ? (p3 - b3) : (b3 + p3);
        }
        float4 o;
        o.x = b0 * scale;
        o.y = b1 * scale;
        o.z = b2 * scale;
        o.w = b3 * scale;
        y[g] = o;
    }
}

extern "C" void kernel_launch(void* const* d_in, const int* in_sizes, int n_in,
                              void* d_out, int out_size, void* d_ws, size_t ws_size,
                              hipStream_t stream) {
    const float4* x = (const float4*)d_in[0];
    float4* y = (float4*)d_out;
    const int n4 = out_size / 4;  // 67,108,864 / 4 = 16,777,216 float4s
    const int threads = 256;
    const int blocks = 2048;  // 8192 waves = 32/CU; grid-stride covers the rest
    BlockHadamardTransform_88957362634992_kernel<<<blocks, threads, 0, stream>>>(x, y, n4);
}